// Round 16
// baseline (122.183 us; speedup 1.0000x reference)
//
#include <hip/hip_runtime.h>
#include <hip/hip_bf16.h>
#include <math.h>

#define B_DIM 8192
#define IN_F  1024
#define OUT_F 1024
#define NSTEP 160                    // 32 g-groups x 5 slabs (K=5120)
#define TILEB 16384                  // one step-tile: 256 rows/cols x 32 k x 2B
#define NT    80                     // K-tiles per half (K-split 2)

typedef unsigned short u16;
typedef unsigned int u32;
typedef __attribute__((ext_vector_type(8))) short bf16x8;
typedef __attribute__((ext_vector_type(8))) unsigned short u16x8;
typedef __attribute__((ext_vector_type(4))) float f32x4;

#define GLOBAL_AS __attribute__((address_space(1)))
#define LDS_AS    __attribute__((address_space(3)))

__device__ __forceinline__ void gload16(const void* g, void* l) {
    __builtin_amdgcn_global_load_lds((const GLOBAL_AS unsigned int*)g,
                                     (LDS_AS unsigned int*)l, 16, 0, 0);
}

__device__ __forceinline__ u16 f2bf(float v) {
    u32 u = __float_as_uint(v);
    return (u16)((u + 0x7FFFu + ((u >> 16) & 1u)) >> 16);
}

__device__ __forceinline__ u32 cvt_pk(float lo, float hi) {
    u32 r;
    asm("v_cvt_pk_bf16_f32 %0, %1, %2" : "=v"(r) : "v"(lo), "v"(hi));
    return r;
}

// x-space step threshold for grid value gv: smallest f32 T with
// (x >= T) <=> ((double)x > atanh(midpoint(gv, prevfloat(gv)))) —
// replicates a correctly-rounded tanh's interval comparisons.
__device__ __forceinline__ float step_threshold(float gv) {
    float below = nextafterf(gv, -2.0f);
    double mid = 0.5 * ((double)gv + (double)below);
    double t = atanh(mid);
    float Tf = (float)t;
    if (!((double)Tf > t)) Tf = nextafterf(Tf, 3.0f);
    return Tf;
}

// ---------------------------------------------------------------------------
// prep kernel — one launch, three sections by blockIdx (R15, unchanged):
//   bid 0..511    : pack_B  (4 panels x 256 cols)
//   bid 512..767  : bias[o] = sum_i sw[o,i,0]
//   bid 768..4863 : pack_A  (32 panels x 256 rows)
// Tile byte = ((panel*160 + t)*16384) + sub*1024 + lane*16 for both images.
// ---------------------------------------------------------------------------
__global__ __launch_bounds__(256) void prep_kernel(
    const float* __restrict__ x, const float* __restrict__ sw,
    const float* __restrict__ bw, const float* __restrict__ grid,
    char* __restrict__ At, char* __restrict__ Bt, float* __restrict__ biasT)
{
    int bid = blockIdx.x;
    int tid = threadIdx.x;

    if (bid < 512) {                                // ---- pack_B ----
        int gid  = bid * 256 + tid;
        int lane = gid & 63;
        int wav  = gid >> 6;                        // 0..2047
        int g    = wav & 31;
        int sn   = (wav >> 5) & 15;
        int p    = wav >> 9;                        // 0..3
        int fc   = lane & 15;
        int q    = lane >> 4;

        int o  = p * 256 + sn * 16 + fc;
        int i0 = g * 32 + q * 8;

        size_t tb = ((size_t)(p * NSTEP + g * 5)) * TILEB
                  + (size_t)sn * 1024 + (size_t)lane * 16;

        const float* bwr = bw + (size_t)o * IN_F + i0;
        float4 b0 = *(const float4*)bwr;
        float4 b1 = *(const float4*)(bwr + 4);
        float v[8] = {b0.x, b0.y, b0.z, b0.w, b1.x, b1.y, b1.z, b1.w};
        u16x8 s0;
        #pragma unroll
        for (int j = 0; j < 8; ++j) s0[j] = f2bf(v[j]);
        *(u16x8*)(Bt + tb) = s0;                    // s = 0

        float c[8][5];
        #pragma unroll
        for (int j = 0; j < 8; ++j) {
            const float* swr = sw + ((size_t)o * IN_F + i0 + j) * 8;
            float4 lo = *(const float4*)swr;
            float4 hi = *(const float4*)(swr + 4);
            c[j][0] = lo.x; c[j][1] = lo.y; c[j][2] = lo.z;
            c[j][3] = lo.w; c[j][4] = hi.x;
        }
        #pragma unroll
        for (int s = 1; s < 5; ++s) {
            u16x8 d;
            #pragma unroll
            for (int j = 0; j < 8; ++j) d[j] = f2bf(c[j][s] - c[j][s - 1]);
            *(u16x8*)(Bt + tb + (size_t)s * TILEB) = d;
        }
    } else if (bid < 768) {                         // ---- bias ----
        int o    = (bid - 512) * 4 + (tid >> 6);
        int lane = tid & 63;
        float s = 0.f;
        #pragma unroll
        for (int j = 0; j < 16; ++j)
            s += sw[((size_t)o * IN_F + j * 64 + lane) * 8];
        #pragma unroll
        for (int off = 32; off; off >>= 1)
            s += __shfl_down(s, off);
        if (lane == 0) biasT[o] = s;
    } else {                                        // ---- pack_A ----
        __shared__ float thr[4];
        if (tid == 0) {
            #pragma unroll
            for (int k = 0; k < 4; ++k)
                thr[k] = step_threshold(grid[k + 1]);   // -0.6,-0.2,0.2,0.6
        }
        __syncthreads();
        float T1 = thr[0], T2 = thr[1], T3 = thr[2], T4 = thr[3];

        int gid  = (bid - 768) * 256 + tid;         // 0 .. 1,048,575
        int lane = gid & 63;
        int wav  = gid >> 6;                        // 0..16383
        int g    = wav & 31;
        int sm   = (wav >> 5) & 15;
        int p    = wav >> 9;                        // 0..31
        int fr   = lane & 15;
        int q    = lane >> 4;

        int b  = p * 256 + sm * 16 + fr;
        int i0 = g * 32 + q * 8;

        const float* xr = x + (size_t)b * IN_F + i0;
        float4 a0 = *(const float4*)xr;
        float4 a1 = *(const float4*)(xr + 4);
        float v[8] = {a0.x, a0.y, a0.z, a0.w, a1.x, a1.y, a1.z, a1.w};

        size_t tb = ((size_t)(p * NSTEP + g * 5)) * TILEB
                  + (size_t)sm * 1024 + (size_t)lane * 16;

        {
            union { u32 u[4]; u16x8 s; } wpk;
            #pragma unroll
            for (int j = 0; j < 4; ++j) wpk.u[j] = cvt_pk(v[2*j], v[2*j+1]);
            *(u16x8*)(At + tb) = wpk.s;             // s = 0: bf16(x)
        }
        float T[4] = {T1, T2, T3, T4};
        #pragma unroll
        for (int s = 0; s < 4; ++s) {
            union { u32 u[4]; u16x8 t; } o;
            #pragma unroll
            for (int j = 0; j < 4; ++j)
                o.u[j] = (v[2*j]     >= T[s] ? 0x00003F80u : 0u)
                       | (v[2*j + 1] >= T[s] ? 0x3F800000u : 0u);
            *(u16x8*)(At + tb + (size_t)(s + 1) * TILEB) = o.t;
        }
    }
}

// ---------------------------------------------------------------------------
// GEMM half (8-phase schedule): 256x256 tile, K-split 2, 80 step-tiles BK=32.
// Grid 256 = 1 block/CU; 512 threads = 8 waves (2 row-halves x 4 col-qtrs);
// wave = 128x64 out. Each step-tile = 2 phases (m201 cadence, 16 MFMA each):
//   phase A: ds_read af[0..4)+bf[0..4) || issue A-half of stage(t+3);
//            barrier; lgkmcnt(0); setprio(1); 16 MFMA m=0..4; setprio(0); barrier
//   phase B: ds_read af[4..8) || issue B-half of stage(t+3); barrier;
//            lgkmcnt(0); 16 MFMA m=4..8; WAITV(8) [drains t+1, leaves 8]; barrier
// 4-slot x 32KB LDS ring; raw barriers, explicit waits only (rule #18).
// kh=0 writes out (+bias); kh=1 writes bf16 partial to p1.
// ---------------------------------------------------------------------------
#define WAITV(N)  asm volatile("s_waitcnt vmcnt(" #N ")" ::: "memory")
#define WAITLGKM  do { asm volatile("s_waitcnt lgkmcnt(0)" ::: "memory");     \
                       __builtin_amdgcn_sched_barrier(0); } while (0)
#define FENCE     asm volatile("" ::: "memory")

__global__ __launch_bounds__(512, 2) void gemm_half_kernel(
    const char* __restrict__ At, const char* __restrict__ Bt,
    const float* __restrict__ biasT, float* __restrict__ out,
    u16* __restrict__ p1)
{
    __shared__ __align__(16) char lds[4 * 32768];   // 128 KB ring

    int tid = threadIdx.x;
    int bid = blockIdx.x;                           // 0..255

    int xcd = bid & 7;
    int r   = bid >> 3;                             // 0..31
    int bcol = r & 3;
    int gh  = r >> 2;                               // 0..7
    int g   = (gh << 3) | xcd;                      // 0..63
    int brow = g >> 1;                              // 0..31
    int kh  = g & 1;                                // K half

    int lane = tid & 63;
    int w    = tid >> 6;                            // 0..7
    int wr   = w >> 2;                              // row half (128 rows)
    int wc   = w & 3;                               // col quarter (64 cols)
    int fr   = lane & 15;
    int q    = lane >> 4;

    const char* Ap = At + ((size_t)brow * NSTEP + (size_t)kh * NT) * TILEB;
    const char* Bp = Bt + ((size_t)bcol * NSTEP + (size_t)kh * NT) * TILEB;

    f32x4 acc[8][4];
    #pragma unroll
    for (int m = 0; m < 8; ++m)
        #pragma unroll
        for (int n = 0; n < 4; ++n)
            #pragma unroll
            for (int j = 0; j < 4; ++j)
                acc[m][n][j] = 0.0f;

    #define STAGE_AH(T) do {                                                  \
        const char* _sa = Ap + (size_t)(T) * TILEB;                           \
        char* _d = lds + ((T) & 3) * 32768;                                   \
        gload16(_sa + tid * 16,        _d + tid * 16);                        \
        gload16(_sa + tid * 16 + 8192, _d + tid * 16 + 8192);                 \
    } while (0)
    #define STAGE_BH(T) do {                                                  \
        const char* _sb = Bp + (size_t)(T) * TILEB;                           \
        char* _d = lds + ((T) & 3) * 32768 + 16384;                           \
        gload16(_sb + tid * 16,        _d + tid * 16);                        \
        gload16(_sb + tid * 16 + 8192, _d + tid * 16 + 8192);                 \
    } while (0)

    // prologue: stage tiles 0,1,2 fully (12 ops); drain tile 0; publish.
    STAGE_AH(0); STAGE_BH(0);
    STAGE_AH(1); STAGE_BH(1);
    STAGE_AH(2); STAGE_BH(2);
    WAITV(8);
    __builtin_amdgcn_s_barrier();
    FENCE;

    #pragma unroll 1
    for (int t = 0; t < NT; ++t) {
        const char* slot = lds + (t & 3) * 32768;
        // ---- phase A ----
        bf16x8 af[4], bfv[4];
        #pragma unroll
        for (int m = 0; m < 4; ++m)
            af[m] = *(const bf16x8*)(slot + (wr * 8 + m) * 1024 + lane * 16);
        #pragma unroll
        for (int n = 0; n < 4; ++n)
            bfv[n] = *(const bf16x8*)(slot + 16384 + (wc * 4 + n) * 1024 + lane * 16);
        if (t + 3 < NT) STAGE_AH(t + 3);
        __builtin_amdgcn_s_barrier();
        WAITLGKM;
        __builtin_amdgcn_s_setprio(1);
        #pragma unroll
        for (int m = 0; m < 4; ++m)
            #pragma unroll
            for (int n = 0; n < 4; ++n)
                acc[m][n] = __builtin_amdgcn_mfma_f32_16x16x32_bf16(
                    af[m], bfv[n], acc[m][n], 0, 0, 0);
        __builtin_amdgcn_s_setprio(0);
        __builtin_amdgcn_s_barrier();
        FENCE;
        // ---- phase B ----
        bf16x8 ag[4];
        #pragma unroll
        for (int m = 0; m < 4; ++m)
            ag[m] = *(const bf16x8*)(slot + (wr * 8 + 4 + m) * 1024 + lane * 16);
        if (t + 3 < NT) STAGE_BH(t + 3);
        __builtin_amdgcn_s_barrier();
        WAITLGKM;
        __builtin_amdgcn_s_setprio(1);
        #pragma unroll
        for (int m = 0; m < 4; ++m)
            #pragma unroll
            for (int n = 0; n < 4; ++n)
                acc[4 + m][n] = __builtin_amdgcn_mfma_f32_16x16x32_bf16(
                    ag[m], bfv[n], acc[4 + m][n], 0, 0, 0);
        __builtin_amdgcn_s_setprio(0);
        // end-of-tile: publish stage(t+1) without draining the queue
        if (t < NT - 3)       WAITV(8);
        else if (t == NT - 3) WAITV(4);
        else if (t == NT - 2) WAITV(0);
        __builtin_amdgcn_s_barrier();
        FENCE;
    }
    #undef STAGE_AH
    #undef STAGE_BH

    // epilogue: C/D layout col = lane&15, row = (lane>>4)*4 + reg
    int crow0 = brow * 256 + wr * 128 + (q << 2);
    int ccol0 = bcol * 256 + wc * 64 + fr;
    if (kh == 0) {
        float bv[4];
        #pragma unroll
        for (int n = 0; n < 4; ++n) bv[n] = biasT[ccol0 + n * 16];
        #pragma unroll
        for (int m = 0; m < 8; ++m)
            #pragma unroll
            for (int j = 0; j < 4; ++j) {
                size_t rr = (size_t)(crow0 + m * 16 + j);
                float* cp = out + rr * OUT_F + ccol0;
                #pragma unroll
                for (int n = 0; n < 4; ++n)
                    cp[n * 16] = acc[m][n][j] + bv[n];
            }
    } else {
        #pragma unroll
        for (int m = 0; m < 8; ++m)
            #pragma unroll
            for (int j = 0; j < 4; ++j) {
                size_t rr = (size_t)(crow0 + m * 16 + j);
                u16* cp = p1 + rr * OUT_F + ccol0;
                #pragma unroll
                for (int n = 0; n < 4; ++n)
                    cp[n * 16] = f2bf(acc[m][n][j]);
            }
    }
}

// ---------------------------------------------------------------------------
// reduce: out += f32(p1)   (8 elems/thread, vectorized)
// ---------------------------------------------------------------------------
__global__ __launch_bounds__(256) void reduce_kernel(
    float* __restrict__ out, const u16* __restrict__ p1)
{
    int i = (blockIdx.x * 256 + threadIdx.x) * 8;
    u16x8 pv = *(const u16x8*)(p1 + i);
    float4 a0 = *(const float4*)(out + i);
    float4 a1 = *(const float4*)(out + i + 4);
    float av[8] = {a0.x, a0.y, a0.z, a0.w, a1.x, a1.y, a1.z, a1.w};
    #pragma unroll
    for (int j = 0; j < 8; ++j)
        av[j] += __uint_as_float(((u32)pv[j]) << 16);
    float4 r0 = {av[0], av[1], av[2], av[3]};
    float4 r1 = {av[4], av[5], av[6], av[7]};
    *(float4*)(out + i)     = r0;
    *(float4*)(out + i + 4) = r1;
}

// Fallback signal if workspace is too small: absmax will read ~12345.
__global__ void sentinel_kernel(float* out, int n) {
    int i = blockIdx.x * 256 + threadIdx.x;
    if (i < n) out[i] = (i == 0) ? 12345.0f : 0.0f;
}

extern "C" void kernel_launch(void* const* d_in, const int* in_sizes, int n_in,
                              void* d_out, int out_size, void* d_ws, size_t ws_size,
                              hipStream_t stream) {
    const float* x    = (const float*)d_in[0];
    const float* sw   = (const float*)d_in[1];
    const float* bw   = (const float*)d_in[2];
    const float* grid = (const float*)d_in[3];
    float* out = (float*)d_out;

    const size_t A_bytes  = (size_t)32 * NSTEP * TILEB;     // 83,886,080
    const size_t B_bytes  = (size_t)4  * NSTEP * TILEB;     // 10,485,760
    const size_t p1_bytes = (size_t)B_DIM * OUT_F * 2;      // 16,777,216
    const size_t bias_bytes = 1024 * sizeof(float);
    if (ws_size < A_bytes + B_bytes + p1_bytes + bias_bytes) {
        sentinel_kernel<<<(out_size + 255) / 256, 256, 0, stream>>>(out, out_size);
        return;
    }

    char*  At    = (char*)d_ws;
    char*  Bt    = (char*)d_ws + A_bytes;
    u16*   p1    = (u16*)((char*)d_ws + A_bytes + B_bytes);
    float* biasT = (float*)((char*)d_ws + A_bytes + B_bytes + p1_bytes);

    prep_kernel<<<4864, 256, 0, stream>>>(x, sw, bw, grid, At, Bt, biasT);
    gemm_half_kernel<<<256, 512, 0, stream>>>(At, Bt, biasT, out, p1);
    reduce_kernel<<<B_DIM * OUT_F / 2048, 256, 0, stream>>>(out, p1);
}